// Round 14
// baseline (174.945 us; speedup 1.0000x reference)
//
#include <hip/hip_runtime.h>

// CP-decomposed 3D conv (AirConv3D): B=1, Cin=32, Cout=64, 56^3, K=3, pad=1, rank=53.
// All-f32. VERDICTS: k3 in-block pipelining loses to cross-block TLP (R13-R20);
// k1d occupancy splits don't help (R17/R21: 40us flat) -> bottleneck is
// work-per-x-load (each block pays ~900cyc load latency; 6-rank batch = only
// ~800cyc work). Toolchain: __launch_bounds__ 2nd arg ~ min blocks/CU.
// R22:
//  k3z: 256-thread blocks, z-SPLIT channels (block = 32 ch, 4 waves x 8ch,
//       a[8]f2 -> VGPR ~46 under (256,8) cap 64). Grid 2744 -> 8 resident
//       blocks/CU = 32 waves, 8 independent barrier domains. XCD swizzle on
//       bid>>1 so z-pairs (same cols, both ch-halves) share an XCD L2.
//       Staging duplicated per z-pair (+~2us VALU) - paid for by occupancy.
//  k1d: 4-way rank split (13-14 ranks/block = 2x work per x-load), shfls in
//       sub-batches of 5 (acc/lm/rp 15 live regs -> ~58 total <= 64).
// Go/no-go: k3z VGPR<=50 & WRITE==43904KB; k1d invisible in top-5.
// NOTE: one ~43us fillBuffer (268MB ws re-poison) sits in the timed window.
// Pipeline: k0_t -> k1d -> k3z. Fallback (small ws): R5 pipeline (known good).

#define NP 175616   // 56*56*56
#define NP2 87808   // NP/2 float2 columns
#define HSTR 3136   // 56*56
#define H2 1568     // HSTR/2 float2 per h-plane
#define W2 28       // 56/2 float2 per w-row
#define CIN 32
#define RK 53
#define RC0 27      // k3 chunk 0 ranks [0,27)
#define COUT 64
#define SCR 53      // fallback scratch slice base in d_out

// ---- k0: Ut[r*32+c] = Ucin[c*53+r] ----
__global__ __launch_bounds__(256) void k0_t(const float* __restrict__ Ucin,
                                            float* __restrict__ Ut)
{
    int t = blockIdx.x * 256 + threadIdx.x;
    if (t < RK * CIN) {
        int r = t >> 5, c = t & 31;
        Ut[t] = Ucin[c * RK + r];
    }
}

// ---- k1d: T1d[r,p] = d-conv(sum_c x[c,p]*Ut[r][c]) ----
// Block = 4 waves; wave = one (h,w) row (lanes 0..55 = d). blockIdx.y in
// [0,4): ranks [13y, 13y+13) (last: [39,53) = 14). Sub-batches of 5 keep
// acc/lm/rp at 15 live regs; 10 independent shfls per sub-batch.
__global__ __launch_bounds__(256, 8) void k1d(
    const float* __restrict__ x, const float* __restrict__ Ut,
    const float* __restrict__ Ukd, float* __restrict__ T1d)
{
    const int lane = threadIdx.x & 63;          // d index
    const int row  = blockIdx.x * 4 + (threadIdx.x >> 6);   // (h,w) row in [0,3136)
    const int p    = row * 56 + lane;
    const bool act = (lane < 56);
    const int pc   = act ? p : (p - 8);         // clamp: lanes 56..63 in-bounds

    float xv[CIN];
#pragma unroll
    for (int c = 0; c < CIN; ++c) xv[c] = x[c * NP + pc];
#pragma unroll
    for (int c = 0; c < CIN; ++c) asm volatile("" : "+v"(xv[c]));  // pin in VGPRs

    const int r0 = blockIdx.y * 13;             // 0,13,26,39
    const int r1 = (blockIdx.y == 3) ? RK : (r0 + 13);

#pragma unroll 1
    for (int rs = r0; rs < r1; rs += 5) {
        const int nb = (r1 - rs < 5) ? (r1 - rs) : 5;
        float acc[5], lm[5], rp[5];
        // dots (independent 4-partial chains)
#pragma unroll
        for (int j = 0; j < 5; ++j) {
            if (j < nb) {
                const float* U = Ut + (rs + j) * CIN;    // uniform -> s_load
                float a0 = 0.f, a1 = 0.f, a2 = 0.f, a3 = 0.f;
#pragma unroll
                for (int c = 0; c < CIN; c += 4) {
                    a0 += xv[c]     * U[c];
                    a1 += xv[c + 1] * U[c + 1];
                    a2 += xv[c + 2] * U[c + 2];
                    a3 += xv[c + 3] * U[c + 3];
                }
                acc[j] = (a0 + a1) + (a2 + a3);
            }
        }
        // shfls back-to-back (independent -> DS pipelines)
#pragma unroll
        for (int j = 0; j < 5; ++j) {
            if (j < nb) {
                lm[j] = __shfl_up(acc[j], 1, 64);
                rp[j] = __shfl_down(acc[j], 1, 64);
            }
        }
        // blend + store
#pragma unroll
        for (int j = 0; j < 5; ++j) {
            if (j < nb) {
                const int r = rs + j;
                float l  = (lane == 0)  ? 0.f : lm[j];
                float rv = (lane == 55) ? 0.f : rp[j];
                float res = l * Ukd[r] + acc[j] * Ukd[RK + r] + rv * Ukd[2 * RK + r];
                if (act) T1d[(size_t)r * NP + p] = res;
            }
        }
    }
}

// ---- k3z: two-phase chunked w+h conv + proj + bias, channel-z-split ----
// 256 threads (4 waves). Work id swz in [0,2744): bx = swz>>1 picks 64 float2
// cols, z = swz&1 picks channel half (32 ch; 8 per wave). z-pairs adjacent in
// swz -> same XCD -> shared L2 for the duplicate T1 reads.
__global__ __launch_bounds__(256, 8) void k3z(
    const float2* __restrict__ Ta, const float* __restrict__ Ucout,
    const float* __restrict__ bias, const float* __restrict__ Ukh,
    const float* __restrict__ Ukw, float2* __restrict__ Out)
{
    __shared__ float2 tld[RC0][64];              // 13824 B

    const int lane = threadIdx.x & 63;
    const int wv   = threadIdx.x >> 6;           // 0..3

    // bijective XCD swizzle (m204); nwg = 2744 (divisible by 8: qx=343, rx=0)
    const int nwg = gridDim.x;
    const int qx = nwg >> 3, rx = nwg & 7;
    const int xcd = blockIdx.x & 7, loc = blockIdx.x >> 3;
    const int swz = ((xcd < rx) ? xcd * (qx + 1) : rx * (qx + 1) + (xcd - rx) * qx) + loc;

    const int bx = swz >> 1;                     // col-block in [0,1372)
    const int z  = swz & 1;                      // channel half

    const int q  = bx * 64 + lane;               // float2 column in [0,NP2)
    const int h  = q / H2;
    const int rm = q - h * H2;
    const int w  = rm / W2;
    const int om = (h > 0)  ? -H2 : 0;
    const int op = (h < 55) ?  H2 : 0;
    const int oa = (w > 0)  ? -W2 : 0;
    const int oc = (w < 55) ?  W2 : 0;
    const float mh0 = (h > 0)  ? 1.f : 0.f;
    const float mh2 = (h < 55) ? 1.f : 0.f;
    const float mw0 = (w > 0)  ? 1.f : 0.f;
    const float mw2 = (w < 55) ? 1.f : 0.f;

    const float2* Sq = Ta + q;
    const int og = __builtin_amdgcn_readfirstlane(z * 32 + (wv << 3)); // 8-ch group

    float2 a[8];

    // ================= chunk 0: ranks [0,27) =================
#pragma unroll 1
    for (int r = wv; r < RC0; r += 4) {
        const float2* S = Sq + (size_t)r * NP2;
        const float kw0 = mw0 * Ukw[r];
        const float kw1 = Ukw[RK + r];
        const float kw2 = mw2 * Ukw[2 * RK + r];
        const float kh0 = mh0 * Ukh[r];
        const float kh1 = Ukh[RK + r];
        const float kh2 = mh2 * Ukh[2 * RK + r];
        float2 v00 = S[om + oa], v01 = S[om], v02 = S[om + oc];
        float2 v10 = S[oa],      v11 = S[0],  v12 = S[oc];
        float2 v20 = S[op + oa], v21 = S[op], v22 = S[op + oc];
        float2 t;
        t.x = (v00.x * kw0 + v01.x * kw1 + v02.x * kw2) * kh0
            + (v10.x * kw0 + v11.x * kw1 + v12.x * kw2) * kh1
            + (v20.x * kw0 + v21.x * kw1 + v22.x * kw2) * kh2;
        t.y = (v00.y * kw0 + v01.y * kw1 + v02.y * kw2) * kh0
            + (v10.y * kw0 + v11.y * kw1 + v12.y * kw2) * kh1
            + (v20.y * kw0 + v21.y * kw1 + v22.y * kw2) * kh2;
        tld[r][lane] = t;
    }
    __syncthreads();

#pragma unroll
    for (int o = 0; o < 8; ++o) {
        float b = bias[og + o];
        a[o].x = b; a[o].y = b;
    }
#pragma unroll 4
    for (int r = 0; r < RC0; ++r) {
        float2 t = tld[r][lane];
        const float* Ur = Ucout + r * COUT + og;         // uniform -> s_load
#pragma unroll
        for (int o = 0; o < 8; ++o) {
            float u = Ur[o];
            a[o].x += t.x * u; a[o].y += t.y * u;
        }
    }
    __syncthreads();                                     // protect LDS overwrite

    // ================= chunk 1: ranks [27,53) =================
#pragma unroll 1
    for (int r = RC0 + wv; r < RK; r += 4) {
        const float2* S = Sq + (size_t)r * NP2;
        const float kw0 = mw0 * Ukw[r];
        const float kw1 = Ukw[RK + r];
        const float kw2 = mw2 * Ukw[2 * RK + r];
        const float kh0 = mh0 * Ukh[r];
        const float kh1 = Ukh[RK + r];
        const float kh2 = mh2 * Ukh[2 * RK + r];
        float2 v00 = S[om + oa], v01 = S[om], v02 = S[om + oc];
        float2 v10 = S[oa],      v11 = S[0],  v12 = S[oc];
        float2 v20 = S[op + oa], v21 = S[op], v22 = S[op + oc];
        float2 t;
        t.x = (v00.x * kw0 + v01.x * kw1 + v02.x * kw2) * kh0
            + (v10.x * kw0 + v11.x * kw1 + v12.x * kw2) * kh1
            + (v20.x * kw0 + v21.x * kw1 + v22.x * kw2) * kh2;
        t.y = (v00.y * kw0 + v01.y * kw1 + v02.y * kw2) * kh0
            + (v10.y * kw0 + v11.y * kw1 + v12.y * kw2) * kh1
            + (v20.y * kw0 + v21.y * kw1 + v22.y * kw2) * kh2;
        tld[r - RC0][lane] = t;
    }
    __syncthreads();

#pragma unroll 4
    for (int r = RC0; r < RK; ++r) {
        float2 t = tld[r - RC0][lane];
        const float* Ur = Ucout + r * COUT + og;
#pragma unroll
        for (int o = 0; o < 8; ++o) {
            float u = Ur[o];
            a[o].x += t.x * u; a[o].y += t.y * u;
        }
    }

#pragma unroll
    for (int o = 0; o < 8; ++o)
        Out[(size_t)(og + o) * NP2 + q] = a[o];
}

// ===================== fallback path (R5, known good) =====================

__global__ __launch_bounds__(256) void k1_chunk(
    const float* __restrict__ x, const float* __restrict__ Ucin,
    float* T, int r0, int nr)
{
    __shared__ float sU[11 * CIN];
    const int tid = threadIdx.x;
    for (int t = tid; t < nr * CIN; t += 256) {
        int lr = t >> 5, c = t & 31;
        sU[t] = Ucin[c * RK + (r0 + lr)];
    }
    __syncthreads();
    const int p = blockIdx.x * 256 + tid;
    float xv[CIN];
#pragma unroll
    for (int c = 0; c < CIN; ++c) xv[c] = x[c * NP + p];
#pragma unroll 1
    for (int lr = 0; lr < nr; ++lr) {
        float acc = 0.f;
#pragma unroll
        for (int c = 0; c < CIN; ++c) acc += xv[c] * sU[lr * CIN + c];
        T[(size_t)(SCR + lr) * NP + p] = acc;
    }
}

__global__ __launch_bounds__(256) void k2_chunk(
    const float* __restrict__ Ukh, const float* __restrict__ Ukw,
    const float* __restrict__ Ukd, float* T, int r0)
{
    __shared__ float sIn[5800];
    __shared__ float sA[5600];
    const int lr = blockIdx.z;
    const int r  = r0 + lr;
    const int h0 = blockIdx.x * 8, w0 = blockIdx.y * 8;
    const int tid = threadIdx.x;
    const float kh0 = Ukh[r], kh1 = Ukh[RK + r], kh2 = Ukh[2 * RK + r];
    const float kw0 = Ukw[r], kw1 = Ukw[RK + r], kw2 = Ukw[2 * RK + r];
    const float kd0 = Ukd[r], kd1 = Ukd[RK + r], kd2 = Ukd[2 * RK + r];
    const float* T1r = T + (size_t)(SCR + lr) * NP;

    for (int idx = tid; idx < 5800; idx += 256) {
        int d = idx % 58; int t2 = idx / 58; int ww = t2 % 10; int hh = t2 / 10;
        int gh = h0 + hh - 1, gw = w0 + ww - 1, gd = d - 1;
        float v = 0.f;
        if ((unsigned)gh < 56u && (unsigned)gw < 56u && (unsigned)gd < 56u)
            v = T1r[gh * HSTR + gw * 56 + gd];
        sIn[idx] = v;
    }
    __syncthreads();
    for (int idx = tid; idx < 5600; idx += 256) {
        int d = idx % 56; int t2 = idx / 56; int ww = t2 % 10; int hh = t2 / 10;
        const float* b = &sIn[(hh * 10 + ww) * 58 + d];
        sA[idx] = b[0] * kd0 + b[1] * kd1 + b[2] * kd2;
    }
    __syncthreads();
    const float k00 = kh0 * kw0, k01 = kh0 * kw1, k02 = kh0 * kw2;
    const float k10 = kh1 * kw0, k11 = kh1 * kw1, k12 = kh1 * kw2;
    const float k20 = kh2 * kw0, k21 = kh2 * kw1, k22 = kh2 * kw2;
    for (int idx = tid; idx < 3584; idx += 256) {
        int d = idx % 56; int t2 = idx / 56; int ww = t2 % 8; int hh = t2 / 8;
        const float* a = &sA[(hh * 10 + ww) * 56 + d];
        float acc = a[0]    * k00 + a[56]   * k01 + a[112]  * k02
                  + a[560]  * k10 + a[616]  * k11 + a[672]  * k12
                  + a[1120] * k20 + a[1176] * k21 + a[1232] * k22;
        T[(size_t)r * NP + (h0 + hh) * HSTR + (w0 + ww) * 56 + d] = acc;
    }
}

__global__ __launch_bounds__(256) void k3_out(
    float* T, const float* __restrict__ Ucout, const float* __restrict__ bias)
{
    __shared__ float sUo[RK * COUT];
    __shared__ float sB[COUT];
    const int tid = threadIdx.x;
    for (int t = tid; t < RK * COUT; t += 256) sUo[t] = Ucout[t];
    if (tid < COUT) sB[tid] = bias[tid];
    __syncthreads();
    const int p = blockIdx.x * 256 + tid;
    float acc[COUT];
#pragma unroll
    for (int o = 0; o < COUT; ++o) acc[o] = sB[o];
#pragma unroll 1
    for (int r = 0; r < RK; ++r) {
        float t = T[(size_t)r * NP + p];
        const float* Ur = &sUo[r * COUT];
#pragma unroll
        for (int o = 0; o < COUT; ++o) acc[o] += t * Ur[o];
    }
#pragma unroll
    for (int o = 0; o < COUT; ++o) T[(size_t)o * NP + p] = acc[o];
}

// ===================== launch =====================

extern "C" void kernel_launch(void* const* d_in, const int* in_sizes, int n_in,
                              void* d_out, int out_size, void* d_ws, size_t ws_size,
                              hipStream_t stream)
{
    const float* x     = (const float*)d_in[0];
    const float* Ukh   = (const float*)d_in[1];
    const float* Ukw   = (const float*)d_in[2];
    const float* Ukd   = (const float*)d_in[3];
    const float* Ucin  = (const float*)d_in[4];
    const float* Ucout = (const float*)d_in[5];
    const float* bias  = (const float*)d_in[6];

    const size_t t1_bytes = (size_t)RK * NP * sizeof(float);   // 37.2 MB

    if (ws_size >= t1_bytes + 8192) {
        float* T1 = (float*)d_ws;
        float* Ut = (float*)((char*)d_ws + t1_bytes);          // 6.8 KB
        k0_t<<<7, 256, 0, stream>>>(Ucin, Ut);
        k1d<<<dim3(HSTR / 4, 4), 256, 0, stream>>>(x, Ut, Ukd, T1);  // 3136 blocks
        k3z<<<NP2 / 32, 256, 0, stream>>>((const float2*)T1, Ucout, bias, Ukh,
                                          Ukw, (float2*)d_out);      // 2744 blocks
    } else {
        float* T = (float*)d_out;
        for (int r0 = 0; r0 < RK; r0 += 11) {
            int nr = (RK - r0 < 11) ? (RK - r0) : 11;
            k1_chunk<<<NP / 256, 256, 0, stream>>>(x, Ucin, T, r0, nr);
            k2_chunk<<<dim3(7, 7, nr), 256, 0, stream>>>(Ukh, Ukw, Ukd, T, r0);
        }
        k3_out<<<NP / 256, 256, 0, stream>>>(T, Ucout, bias);
    }
}

// Round 16
// 153.423 us; speedup vs baseline: 1.1403x; 1.1403x over previous
//
#include <hip/hip_runtime.h>

// CP-decomposed 3D conv (AirConv3D): B=1, Cin=32, Cout=64, 56^3, K=3, pad=1, rank=53.
// All-f32. VERDICTS: k3 in-block pipelining loses (R13-R20). R22 k3z z-split:
// occ 43->62% but 73us WORSE (VGPR clamp 32 -> spill) => OCCUPANCY IS NOT K3'S
// CONSTRAINT. Theory: k3c's unroll-1 stage loop serializes ranks -> 9 loads in
// flight/wave; FETCH 28/37MB -> ~75% of stage loads are HBM (~900cyc) ->
// serial latency dominates.
// R23 (recompile: v2 — R15's dst##00.x macro paste was an invalid pp-token;
// now 9-elem arrays with constant indices): k3c2 = k3c + 2-rank batched stage
// (18 loads for r,r+8 back-to-back, then blend both). 2x MLP where it stalls.
// Go/no-go: WRITE==43904KB exactly (no spill), dur 30-36us. If ~43 & no spill:
// k3c is at structural floor.
// k1d: R22 version carried unchanged (4-way split, sub-batch-5 shfls).
// NOTE: one ~43us fillBuffer (268MB ws re-poison) sits in the timed window.
// Pipeline: k0_t -> k1d -> k3c2. Fallback (small ws): R5 pipeline (known good).

#define NP 175616   // 56*56*56
#define NP2 87808   // NP/2 float2 columns
#define HSTR 3136   // 56*56
#define H2 1568     // HSTR/2 float2 per h-plane
#define W2 28       // 56/2 float2 per w-row
#define CIN 32
#define RK 53
#define RC0 27      // k3 chunk 0 ranks [0,27)
#define COUT 64
#define SCR 53      // fallback scratch slice base in d_out

// ---- k0: Ut[r*32+c] = Ucin[c*53+r] ----
__global__ __launch_bounds__(256) void k0_t(const float* __restrict__ Ucin,
                                            float* __restrict__ Ut)
{
    int t = blockIdx.x * 256 + threadIdx.x;
    if (t < RK * CIN) {
        int r = t >> 5, c = t & 31;
        Ut[t] = Ucin[c * RK + r];
    }
}

// ---- k1d: T1d[r,p] = d-conv(sum_c x[c,p]*Ut[r][c]) (R22) ----
__global__ __launch_bounds__(256, 8) void k1d(
    const float* __restrict__ x, const float* __restrict__ Ut,
    const float* __restrict__ Ukd, float* __restrict__ T1d)
{
    const int lane = threadIdx.x & 63;          // d index
    const int row  = blockIdx.x * 4 + (threadIdx.x >> 6);   // (h,w) row in [0,3136)
    const int p    = row * 56 + lane;
    const bool act = (lane < 56);
    const int pc   = act ? p : (p - 8);         // clamp: lanes 56..63 in-bounds

    float xv[CIN];
#pragma unroll
    for (int c = 0; c < CIN; ++c) xv[c] = x[c * NP + pc];
#pragma unroll
    for (int c = 0; c < CIN; ++c) asm volatile("" : "+v"(xv[c]));  // pin in VGPRs

    const int r0 = blockIdx.y * 13;             // 0,13,26,39
    const int r1 = (blockIdx.y == 3) ? RK : (r0 + 13);

#pragma unroll 1
    for (int rs = r0; rs < r1; rs += 5) {
        const int nb = (r1 - rs < 5) ? (r1 - rs) : 5;
        float acc[5], lm[5], rp[5];
#pragma unroll
        for (int j = 0; j < 5; ++j) {
            if (j < nb) {
                const float* U = Ut + (rs + j) * CIN;    // uniform -> s_load
                float a0 = 0.f, a1 = 0.f, a2 = 0.f, a3 = 0.f;
#pragma unroll
                for (int c = 0; c < CIN; c += 4) {
                    a0 += xv[c]     * U[c];
                    a1 += xv[c + 1] * U[c + 1];
                    a2 += xv[c + 2] * U[c + 2];
                    a3 += xv[c + 3] * U[c + 3];
                }
                acc[j] = (a0 + a1) + (a2 + a3);
            }
        }
#pragma unroll
        for (int j = 0; j < 5; ++j) {
            if (j < nb) {
                lm[j] = __shfl_up(acc[j], 1, 64);
                rp[j] = __shfl_down(acc[j], 1, 64);
            }
        }
#pragma unroll
        for (int j = 0; j < 5; ++j) {
            if (j < nb) {
                const int r = rs + j;
                float l  = (lane == 0)  ? 0.f : lm[j];
                float rv = (lane == 55) ? 0.f : rp[j];
                float res = l * Ukd[r] + acc[j] * Ukd[RK + r] + rv * Ukd[2 * RK + r];
                if (act) T1d[(size_t)r * NP + p] = res;
            }
        }
    }
}

// ---- k3c2: two-phase chunked w+h conv + proj + bias, 2-rank batched stage ----
// 512 threads / 8 waves; wave wv stages ranks {c0+wv, c0+wv+8, ...} with TWO
// ranks' 18 loads issued back-to-back before blending (2x MLP vs R16).
__global__ __launch_bounds__(512, 4) void k3c2(
    const float2* __restrict__ Ta, const float* __restrict__ Ucout,
    const float* __restrict__ bias, const float* __restrict__ Ukh,
    const float* __restrict__ Ukw, float2* __restrict__ Out)
{
    __shared__ float2 tld[RC0][64];              // 13824 B

    const int lane = threadIdx.x & 63;
    const int wv   = threadIdx.x >> 6;           // 0..7

    // bijective XCD swizzle (m204); nwg = 1372
    const int nwg = gridDim.x;
    const int qx = nwg >> 3, rx = nwg & 7;
    const int xcd = blockIdx.x & 7, loc = blockIdx.x >> 3;
    const int swz = ((xcd < rx) ? xcd * (qx + 1) : rx * (qx + 1) + (xcd - rx) * qx) + loc;

    const int q  = swz * 64 + lane;              // float2 column in [0,NP2)
    const int h  = q / H2;
    const int rm = q - h * H2;
    const int w  = rm / W2;
    const int om = (h > 0)  ? -H2 : 0;
    const int op = (h < 55) ?  H2 : 0;
    const int oa = (w > 0)  ? -W2 : 0;
    const int oc = (w < 55) ?  W2 : 0;
    const float mh0 = (h > 0)  ? 1.f : 0.f;
    const float mh2 = (h < 55) ? 1.f : 0.f;
    const float mw0 = (w > 0)  ? 1.f : 0.f;
    const float mw2 = (w < 55) ? 1.f : 0.f;

    const float2* Sq = Ta + q;
    const int og = __builtin_amdgcn_readfirstlane(wv << 3);  // 0,8,...,56

    float2 a[8];

    // arrays with compile-time indices only (fully unrolled -> registers)
#define LOAD9(dst, S) { \
    dst[0] = (S)[om + oa]; dst[1] = (S)[om]; dst[2] = (S)[om + oc]; \
    dst[3] = (S)[oa];      dst[4] = (S)[0];  dst[5] = (S)[oc];      \
    dst[6] = (S)[op + oa]; dst[7] = (S)[op]; dst[8] = (S)[op + oc]; }

#define BLEND(dst, t, r) { \
    const float kw0 = mw0 * Ukw[r]; \
    const float kw1 = Ukw[RK + (r)]; \
    const float kw2 = mw2 * Ukw[2 * RK + (r)]; \
    const float kh0 = mh0 * Ukh[r]; \
    const float kh1 = Ukh[RK + (r)]; \
    const float kh2 = mh2 * Ukh[2 * RK + (r)]; \
    t.x = (dst[0].x * kw0 + dst[1].x * kw1 + dst[2].x * kw2) * kh0 \
        + (dst[3].x * kw0 + dst[4].x * kw1 + dst[5].x * kw2) * kh1 \
        + (dst[6].x * kw0 + dst[7].x * kw1 + dst[8].x * kw2) * kh2; \
    t.y = (dst[0].y * kw0 + dst[1].y * kw1 + dst[2].y * kw2) * kh0 \
        + (dst[3].y * kw0 + dst[4].y * kw1 + dst[5].y * kw2) * kh1 \
        + (dst[6].y * kw0 + dst[7].y * kw1 + dst[8].y * kw2) * kh2; }

    float2 vA[9], vB[9];

    // ================= chunk 0: ranks [0,27) =================
#pragma unroll 1
    for (int rb = wv; rb < RC0; rb += 16) {
        const int rA = rb, rB = rb + 8;
        const bool hB = (rB < RC0);              // wave-uniform
        LOAD9(vA, Sq + (size_t)rA * NP2);
        if (hB) { LOAD9(vB, Sq + (size_t)rB * NP2); }
        float2 tA; BLEND(vA, tA, rA); tld[rA][lane] = tA;
        if (hB) { float2 tB; BLEND(vB, tB, rB); tld[rB][lane] = tB; }
    }
    __syncthreads();

#pragma unroll
    for (int o = 0; o < 8; ++o) {
        float b = bias[og + o];
        a[o].x = b; a[o].y = b;
    }
#pragma unroll 4
    for (int r = 0; r < RC0; ++r) {
        float2 t = tld[r][lane];
        const float* Ur = Ucout + r * COUT + og;         // uniform -> s_load
#pragma unroll
        for (int o = 0; o < 8; ++o) {
            float u = Ur[o];
            a[o].x += t.x * u; a[o].y += t.y * u;
        }
    }
    __syncthreads();                                     // protect LDS overwrite

    // ================= chunk 1: ranks [27,53), 26 ranks =================
#pragma unroll 1
    for (int rb = RC0 + wv; rb < RK; rb += 16) {
        const int rA = rb, rB = rb + 8;
        const bool hB = (rB < RK);               // wave-uniform
        LOAD9(vA, Sq + (size_t)rA * NP2);
        if (hB) { LOAD9(vB, Sq + (size_t)rB * NP2); }
        float2 tA; BLEND(vA, tA, rA); tld[rA - RC0][lane] = tA;
        if (hB) { float2 tB; BLEND(vB, tB, rB); tld[rB - RC0][lane] = tB; }
    }
    __syncthreads();

#pragma unroll 4
    for (int r = RC0; r < RK; ++r) {
        float2 t = tld[r - RC0][lane];
        const float* Ur = Ucout + r * COUT + og;
#pragma unroll
        for (int o = 0; o < 8; ++o) {
            float u = Ur[o];
            a[o].x += t.x * u; a[o].y += t.y * u;
        }
    }

#pragma unroll
    for (int o = 0; o < 8; ++o)
        Out[(size_t)(og + o) * NP2 + q] = a[o];
#undef LOAD9
#undef BLEND
}

// ===================== fallback path (R5, known good) =====================

__global__ __launch_bounds__(256) void k1_chunk(
    const float* __restrict__ x, const float* __restrict__ Ucin,
    float* T, int r0, int nr)
{
    __shared__ float sU[11 * CIN];
    const int tid = threadIdx.x;
    for (int t = tid; t < nr * CIN; t += 256) {
        int lr = t >> 5, c = t & 31;
        sU[t] = Ucin[c * RK + (r0 + lr)];
    }
    __syncthreads();
    const int p = blockIdx.x * 256 + tid;
    float xv[CIN];
#pragma unroll
    for (int c = 0; c < CIN; ++c) xv[c] = x[c * NP + p];
#pragma unroll 1
    for (int lr = 0; lr < nr; ++lr) {
        float acc = 0.f;
#pragma unroll
        for (int c = 0; c < CIN; ++c) acc += xv[c] * sU[lr * CIN + c];
        T[(size_t)(SCR + lr) * NP + p] = acc;
    }
}

__global__ __launch_bounds__(256) void k2_chunk(
    const float* __restrict__ Ukh, const float* __restrict__ Ukw,
    const float* __restrict__ Ukd, float* T, int r0)
{
    __shared__ float sIn[5800];
    __shared__ float sA[5600];
    const int lr = blockIdx.z;
    const int r  = r0 + lr;
    const int h0 = blockIdx.x * 8, w0 = blockIdx.y * 8;
    const int tid = threadIdx.x;
    const float kh0 = Ukh[r], kh1 = Ukh[RK + r], kh2 = Ukh[2 * RK + r];
    const float kw0 = Ukw[r], kw1 = Ukw[RK + r], kw2 = Ukw[2 * RK + r];
    const float kd0 = Ukd[r], kd1 = Ukd[RK + r], kd2 = Ukd[2 * RK + r];
    const float* T1r = T + (size_t)(SCR + lr) * NP;

    for (int idx = tid; idx < 5800; idx += 256) {
        int d = idx % 58; int t2 = idx / 58; int ww = t2 % 10; int hh = t2 / 10;
        int gh = h0 + hh - 1, gw = w0 + ww - 1, gd = d - 1;
        float v = 0.f;
        if ((unsigned)gh < 56u && (unsigned)gw < 56u && (unsigned)gd < 56u)
            v = T1r[gh * HSTR + gw * 56 + gd];
        sIn[idx] = v;
    }
    __syncthreads();
    for (int idx = tid; idx < 5600; idx += 256) {
        int d = idx % 56; int t2 = idx / 56; int ww = t2 % 10; int hh = t2 / 10;
        const float* b = &sIn[(hh * 10 + ww) * 58 + d];
        sA[idx] = b[0] * kd0 + b[1] * kd1 + b[2] * kd2;
    }
    __syncthreads();
    const float k00 = kh0 * kw0, k01 = kh0 * kw1, k02 = kh0 * kw2;
    const float k10 = kh1 * kw0, k11 = kh1 * kw1, k12 = kh1 * kw2;
    const float k20 = kh2 * kw0, k21 = kh2 * kw1, k22 = kh2 * kw2;
    for (int idx = tid; idx < 3584; idx += 256) {
        int d = idx % 56; int t2 = idx / 56; int ww = t2 % 8; int hh = t2 / 8;
        const float* a = &sA[(hh * 10 + ww) * 56 + d];
        float acc = a[0]    * k00 + a[56]   * k01 + a[112]  * k02
                  + a[560]  * k10 + a[616]  * k11 + a[672]  * k12
                  + a[1120] * k20 + a[1176] * k21 + a[1232] * k22;
        T[(size_t)r * NP + (h0 + hh) * HSTR + (w0 + ww) * 56 + d] = acc;
    }
}

__global__ __launch_bounds__(256) void k3_out(
    float* T, const float* __restrict__ Ucout, const float* __restrict__ bias)
{
    __shared__ float sUo[RK * COUT];
    __shared__ float sB[COUT];
    const int tid = threadIdx.x;
    for (int t = tid; t < RK * COUT; t += 256) sUo[t] = Ucout[t];
    if (tid < COUT) sB[tid] = bias[tid];
    __syncthreads();
    const int p = blockIdx.x * 256 + tid;
    float acc[COUT];
#pragma unroll
    for (int o = 0; o < COUT; ++o) acc[o] = sB[o];
#pragma unroll 1
    for (int r = 0; r < RK; ++r) {
        float t = T[(size_t)r * NP + p];
        const float* Ur = &sUo[r * COUT];
#pragma unroll
        for (int o = 0; o < COUT; ++o) acc[o] += t * Ur[o];
    }
#pragma unroll
    for (int o = 0; o < COUT; ++o) T[(size_t)o * NP + p] = acc[o];
}

// ===================== launch =====================

extern "C" void kernel_launch(void* const* d_in, const int* in_sizes, int n_in,
                              void* d_out, int out_size, void* d_ws, size_t ws_size,
                              hipStream_t stream)
{
    const float* x     = (const float*)d_in[0];
    const float* Ukh   = (const float*)d_in[1];
    const float* Ukw   = (const float*)d_in[2];
    const float* Ukd   = (const float*)d_in[3];
    const float* Ucin  = (const float*)d_in[4];
    const float* Ucout = (const float*)d_in[5];
    const float* bias  = (const float*)d_in[6];

    const size_t t1_bytes = (size_t)RK * NP * sizeof(float);   // 37.2 MB

    if (ws_size >= t1_bytes + 8192) {
        float* T1 = (float*)d_ws;
        float* Ut = (float*)((char*)d_ws + t1_bytes);          // 6.8 KB
        k0_t<<<7, 256, 0, stream>>>(Ucin, Ut);
        k1d<<<dim3(HSTR / 4, 4), 256, 0, stream>>>(x, Ut, Ukd, T1);  // 3136 blocks
        k3c2<<<NP2 / 64, 512, 0, stream>>>((const float2*)T1, Ucout, bias, Ukh,
                                           Ukw, (float2*)d_out);     // 1372 blocks
    } else {
        float* T = (float*)d_out;
        for (int r0 = 0; r0 < RK; r0 += 11) {
            int nr = (RK - r0 < 11) ? (RK - r0) : 11;
            k1_chunk<<<NP / 256, 256, 0, stream>>>(x, Ucin, T, r0, nr);
            k2_chunk<<<dim3(7, 7, nr), 256, 0, stream>>>(Ukh, Ukw, Ukd, T, r0);
        }
        k3_out<<<NP / 256, 256, 0, stream>>>(T, Ucout, bias);
    }
}